// Round 6
// baseline (565.954 us; speedup 1.0000x reference)
//
#include <hip/hip_runtime.h>

// Problem constants
#define TT 128
#define EE 192
#define HH 192
#define SCALE_F 0.07216878364870322f
#define LOG2E_F 1.4426950408889634f

typedef float f32x4 __attribute__((ext_vector_type(4)));
typedef short short8 __attribute__((ext_vector_type(8)));

__device__ inline unsigned short f2bf(float x) {
  union { float f; unsigned u; } v; v.f = x;
  unsigned r = v.u + 0x7FFFu + ((v.u >> 16) & 1u);
  return (unsigned short)(r >> 16);
}
__device__ inline unsigned pack2bf(float a, float b) {
  return (unsigned)f2bf(a) | ((unsigned)f2bf(b) << 16);
}

// ---------------------------------------------------------------------------
// pack_w: W[h][e] fp32 -> frag-major bf16 in ws.
// frag f = widx*72 + tile*6 + es  (widx: 0=Q,1=K,2=V; tile=h/16; es=e/32)
// element: lane(lg,lr), j=0..7 -> W[16*tile+lr][32*es+8*lg+j]
// Each frag is 1KB contiguous: ws[(f*64+lane)*8 + j]
// ---------------------------------------------------------------------------
__global__ void pack_w(const float* __restrict__ Wq, const float* __restrict__ Wk,
                       const float* __restrict__ Wv, short* __restrict__ out) {
  int f = blockIdx.x * 4 + (threadIdx.x >> 6);  // 216 frags, grid 54 x 256
  int lane = threadIdx.x & 63, lg = lane >> 4, lr = lane & 15;
  int widx = f / 72, rem = f % 72, tile = rem / 6, es = rem % 6;
  const float* W = (widx == 0) ? Wq : ((widx == 1) ? Wk : Wv);
  const float* p = W + (16 * tile + lr) * EE + 32 * es + 8 * lg;
  float4 a = *(const float4*)p;
  float4 b = *(const float4*)(p + 4);
  short8 h;
  h[0] = (short)f2bf(a.x); h[1] = (short)f2bf(a.y);
  h[2] = (short)f2bf(a.z); h[3] = (short)f2bf(a.w);
  h[4] = (short)f2bf(b.x); h[5] = (short)f2bf(b.y);
  h[6] = (short)f2bf(b.z); h[7] = (short)f2bf(b.w);
  *(short8*)(out + ((size_t)f * 64 + lane) * 8) = h;
}

// ---------------------------------------------------------------------------
// Fused head kernel. Block = 1 batch, 512 thr (8 waves), 48KB LDS, 3 barriers.
// LDS holds K as QK^T A-fragments [kt 0..7][ha 0..5] (48 x 1KB), then (after
// B2) V as PV B-fragments [tp 0..3][ht 0..11] (48 x 1KB).
// Wave wid: q-tile qt=wid; stages m-tile mt=wid for ALL 12 n-tiles (K and V).
// Register diet targets <=128 total (VGPR+AGPR) so (512,4) -> 4 waves/SIMD.
// ---------------------------------------------------------------------------
__global__ __launch_bounds__(512, 4)
void head_fused(const float* __restrict__ x, const short* __restrict__ wf,
                float* __restrict__ out) {
  extern __shared__ char smem[];  // 49152 B
  const int b = blockIdx.x;
  const int tid = threadIdx.x;
  const int wid = tid >> 6, lane = tid & 63, lg = lane >> 4, lr = lane & 15;
  const int qt = wid;

  const short* wfq = wf;
  const short* wfk = wf + 72 * 64 * 8;
  const short* wfv = wf + 2 * 72 * 64 * 8;
  const f32x4 zero = {0.f, 0.f, 0.f, 0.f};

  // ---- x fragments for own rows 16*wid+lr (used for Q^T, K & V staging) ----
  const float* xb = x + (size_t)b * (TT * EE);
  short8 xq[6];
#pragma unroll
  for (int es = 0; es < 6; ++es) {
    const float* p = xb + (16 * wid + lr) * EE + 32 * es + 8 * lg;
    float4 u = *(const float4*)p, v = *(const float4*)(p + 4);
    short8 h;
    h[0] = (short)f2bf(u.x); h[1] = (short)f2bf(u.y);
    h[2] = (short)f2bf(u.z); h[3] = (short)f2bf(u.w);
    h[4] = (short)f2bf(v.x); h[5] = (short)f2bf(v.y);
    h[6] = (short)f2bf(v.z); h[7] = (short)f2bf(v.w);
    xq[es] = h;
  }

  // ---- Q^T then shuffle to QK B-fragments; wqp scoped to die early ----
  short8 qb[6];
  {
    unsigned wqp[12][2];
#pragma unroll
    for (int ht = 0; ht < 12; ++ht) {
      f32x4 a = zero;
#pragma unroll
      for (int es = 0; es < 6; ++es) {
        short8 wg = *(const short8*)(wfq + ((size_t)(ht * 6 + es) * 64 + lane) * 8);
        a = __builtin_amdgcn_mfma_f32_16x16x32_bf16(wg, xq[es], a, 0, 0, 0);
      }
      wqp[ht][0] = pack2bf(a[0], a[1]);
      wqp[ht][1] = pack2bf(a[2], a[3]);
    }
    // qb[ha]: lane j -> Q[16qt+lr][32ha+8lg+j]
#pragma unroll
    for (int ha = 0; ha < 6; ++ha) {
      union { unsigned d[4]; short8 v; } au;
#pragma unroll
      for (int i = 0; i < 4; ++i) {
        int sl = ((2 * (lg & 1) + (i >> 1)) << 4) | lr;
        unsigned v0 = (unsigned)__shfl((int)wqp[2 * ha][i & 1], sl);
        unsigned v1 = (unsigned)__shfl((int)wqp[2 * ha + 1][i & 1], sl);
        au.d[i] = (lg >> 1) ? v1 : v0;
      }
      qb[ha] = au.v;
    }
  }

  // ---- K staging: tiles (mt=wid, nt=0..11) ----
#pragma unroll
  for (int nt = 0; nt < 12; ++nt) {
    f32x4 a0 = zero;
#pragma unroll
    for (int es = 0; es < 6; ++es) {
      short8 wg = *(const short8*)(wfk + ((size_t)(nt * 6 + es) * 64 + lane) * 8);
      a0 = __builtin_amdgcn_mfma_f32_16x16x32_bf16(xq[es], wg, a0, 0, 0, 0);
    }
    // value K[16*wid+4lg+r][16nt+lr] -> A-frag(kt=wid, ha=nt>>1):
    //   dest lane (lg2=2(nt&1)+(lr>>3), lr2=4lg+r), byte j=lr&7
    int lg2 = 2 * (nt & 1) + (lr >> 3), j = lr & 7;
#pragma unroll
    for (int r = 0; r < 4; ++r)
      *(unsigned short*)(smem +
        (((wid * 6 + (nt >> 1)) * 64 + lg2 * 16 + 4 * lg + r) << 4) + j * 2) = f2bf(a0[r]);
  }
  __syncthreads();  // B1: K fragments visible

  // ---- QK^T, softmax, pack PV A-frags pa[4]; sa/pw scoped to die early ----
  short8 pa[4];
  {
    f32x4 sa[8];
#pragma unroll
    for (int kt = 0; kt < 8; ++kt) sa[kt] = zero;
#pragma unroll
    for (int kt = 0; kt < 8; ++kt) {
      if (kt <= qt) {
#pragma unroll
        for (int ha = 0; ha < 6; ++ha) {
          short8 ka = *(const short8*)(smem + (((kt * 6 + ha) * 64 + lane) << 4));
          sa[kt] = __builtin_amdgcn_mfma_f32_16x16x32_bf16(ka, qb[ha], sa[kt], 0, 0, 0);
        }
      }
    }

    // softmax over row q=16qt+lr (in-lane + 2 shfl_xor across lg)
    const float CSC = SCALE_F * LOG2E_F;
    float m = -INFINITY;
#pragma unroll
    for (int kt = 0; kt < 8; ++kt)
      if (kt <= qt) {
#pragma unroll
        for (int r = 0; r < 4; ++r) {
          float v = sa[kt][r] * CSC;
          if (kt == qt && 4 * lg + r > lr) v = -INFINITY;  // causal diagonal
          sa[kt][r] = v;
          m = fmaxf(m, v);
        }
      }
    m = fmaxf(m, __shfl_xor(m, 16));
    m = fmaxf(m, __shfl_xor(m, 32));
    float sum = 0.f;
#pragma unroll
    for (int kt = 0; kt < 8; ++kt)
      if (kt <= qt) {
#pragma unroll
        for (int r = 0; r < 4; ++r) {
          float p = exp2f(sa[kt][r] - m);
          sa[kt][r] = p;
          sum += p;
        }
      }
    sum += __shfl_xor(sum, 16);
    sum += __shfl_xor(sum, 32);
    const float rinv = 1.0f / sum;

    unsigned pw[8][2];
#pragma unroll
    for (int kt = 0; kt < 8; ++kt) { pw[kt][0] = 0u; pw[kt][1] = 0u; }
#pragma unroll
    for (int kt = 0; kt < 8; ++kt)
      if (kt <= qt) {
        pw[kt][0] = pack2bf(sa[kt][0] * rinv, sa[kt][1] * rinv);
        pw[kt][1] = pack2bf(sa[kt][2] * rinv, sa[kt][3] * rinv);
      }

    // pa[tp]: lane j -> P[q=16qt+lr][t=32tp+8lg+j]
#pragma unroll
    for (int tp = 0; tp < 4; ++tp) {
      union { unsigned d[4]; short8 v; } au;
#pragma unroll
      for (int i = 0; i < 4; ++i) {
        int sl = ((2 * (lg & 1) + (i >> 1)) << 4) | lr;
        unsigned lo = (unsigned)__shfl((int)pw[2 * tp][i & 1], sl);
        unsigned hi = (unsigned)__shfl((int)pw[2 * tp + 1][i & 1], sl);
        au.d[i] = (lg >> 1) ? hi : lo;
      }
      pa[tp] = au.v;
    }
  }
  __syncthreads();  // B2: all K-fragment reads done; LDS reusable for V

  // ---- V staging into PV B-fragments [tp][ht]: tiles (mt=wid, nt=0..11) ----
#pragma unroll
  for (int nt = 0; nt < 12; ++nt) {
    f32x4 a0 = zero;
#pragma unroll
    for (int es = 0; es < 6; ++es) {
      short8 wg = *(const short8*)(wfv + ((size_t)(nt * 6 + es) * 64 + lane) * 8);
      a0 = __builtin_amdgcn_mfma_f32_16x16x32_bf16(xq[es], wg, a0, 0, 0, 0);
    }
    // value V[16*wid+4lg+r][16nt+lr] -> B-frag(tp=wid>>1, ht=nt):
    //   t_local = 16(wid&1)+4lg+r; dest lane (lg2=t_local>>3, lr2=lr), byte j=t_local&7
    int tl = 16 * (wid & 1) + 4 * lg;
#pragma unroll
    for (int r = 0; r < 4; ++r) {
      int t = tl + r;
      int lg2 = t >> 3, j = t & 7;
      *(unsigned short*)(smem +
        ((((wid >> 1) * 12 + nt) * 64 + lg2 * 16 + lr) << 4) + j * 2) = f2bf(a0[r]);
    }
  }
  __syncthreads();  // B3: V fragments visible

  // ---- PV in two ht-halves (o6 = 24 regs instead of 48) ----
  float* ob = out + (size_t)b * (TT * HH);
#pragma unroll
  for (int half = 0; half < 2; ++half) {
    f32x4 o6[6];
#pragma unroll
    for (int n = 0; n < 6; ++n) o6[n] = zero;
#pragma unroll
    for (int tp = 0; tp < 4; ++tp) {
      if (tp <= (qt >> 1)) {
#pragma unroll
        for (int n = 0; n < 6; ++n) {
          int ht = half * 6 + n;
          short8 bv = *(const short8*)(smem + (((tp * 12 + ht) * 64 + lane) << 4));
          o6[n] = __builtin_amdgcn_mfma_f32_16x16x32_bf16(pa[tp], bv, o6[n], 0, 0, 0);
        }
      }
    }
    // store: lane holds O[16qt+4lg+r][16ht+lr]
#pragma unroll
    for (int n = 0; n < 6; ++n)
#pragma unroll
      for (int r = 0; r < 4; ++r)
        ob[(16 * qt + 4 * lg + r) * HH + (half * 6 + n) * 16 + lr] = o6[n][r];
  }
}

extern "C" void kernel_launch(void* const* d_in, const int* in_sizes, int n_in,
                              void* d_out, int out_size, void* d_ws, size_t ws_size,
                              hipStream_t stream) {
  const float* x  = (const float*)d_in[0];
  const float* Wq = (const float*)d_in[1];
  const float* Wk = (const float*)d_in[2];
  const float* Wv = (const float*)d_in[3];
  float* out = (float*)d_out;
  short* wsW = (short*)d_ws;  // 216 frags x 1KB = 221184 B
  int Bn = in_sizes[0] / (TT * EE);

  hipLaunchKernelGGL(pack_w, dim3(54), dim3(256), 0, stream, Wq, Wk, Wv, wsW);
  hipLaunchKernelGGL(head_fused, dim3(Bn), dim3(512), 49152, stream,
                     x, wsW, out);
}

// Round 7
// 407.052 us; speedup vs baseline: 1.3904x; 1.3904x over previous
//
#include <hip/hip_runtime.h>

// Problem constants
#define TT 128
#define EE 192
#define HH 192
#define SCALE_F 0.07216878364870322f
#define LOG2E_F 1.4426950408889634f

typedef float f32x4 __attribute__((ext_vector_type(4)));
typedef short short8 __attribute__((ext_vector_type(8)));

__device__ inline unsigned short f2bf(float x) {
  union { float f; unsigned u; } v; v.f = x;
  unsigned r = v.u + 0x7FFFu + ((v.u >> 16) & 1u);
  return (unsigned short)(r >> 16);
}
__device__ inline unsigned pack2bf(float a, float b) {
  return (unsigned)f2bf(a) | ((unsigned)f2bf(b) << 16);
}

// ---------------------------------------------------------------------------
// pack_w: W[h][e] fp32 -> frag-major bf16 in ws.
// frag f = widx*72 + tile*6 + es  (widx: 0=Q,1=K,2=V; tile=h/16; es=e/32)
// element: lane(lg,lr), j=0..7 -> W[16*tile+lr][32*es+8*lg+j]
// Each frag is 1KB contiguous: ws[(f*64+lane)*8 + j]
// ---------------------------------------------------------------------------
__global__ void pack_w(const float* __restrict__ Wq, const float* __restrict__ Wk,
                       const float* __restrict__ Wv, short* __restrict__ out) {
  int f = blockIdx.x * 4 + (threadIdx.x >> 6);  // 216 frags, grid 54 x 256
  int lane = threadIdx.x & 63, lg = lane >> 4, lr = lane & 15;
  int widx = f / 72, rem = f % 72, tile = rem / 6, es = rem % 6;
  const float* W = (widx == 0) ? Wq : ((widx == 1) ? Wk : Wv);
  const float* p = W + (16 * tile + lr) * EE + 32 * es + 8 * lg;
  float4 a = *(const float4*)p;
  float4 b = *(const float4*)(p + 4);
  short8 h;
  h[0] = (short)f2bf(a.x); h[1] = (short)f2bf(a.y);
  h[2] = (short)f2bf(a.z); h[3] = (short)f2bf(a.w);
  h[4] = (short)f2bf(b.x); h[5] = (short)f2bf(b.y);
  h[6] = (short)f2bf(b.z); h[7] = (short)f2bf(b.w);
  *(short8*)(out + ((size_t)f * 64 + lane) * 8) = h;
}

// ---------------------------------------------------------------------------
// Fused head kernel. Block = 1 batch, 512 thr (8 waves), 48KB LDS, 3 barriers.
// LDS holds K as QK^T A-fragments [kt 0..7][ha 0..5] (48 x 1KB), then (after
// B2) V as PV B-fragments [tp 0..3][ht 0..11] (48 x 1KB).
// Wave wid: q-tile qt=wid; stages m-tile mt=wid for ALL 12 n-tiles (K and V).
// Straight-line (no divergent branches); x reloaded before V staging so xq
// is dead across the QK/softmax peak. Target peak liveness ~64-70 VGPR so
// WPE=4 (128-reg budget, 64V/64A split) fits without spilling.
// ---------------------------------------------------------------------------
template <int WPE>
__global__ __launch_bounds__(512, WPE)
void head_fused(const float* __restrict__ x, const short* __restrict__ wf,
                float* __restrict__ out) {
  extern __shared__ char smem[];  // 49152 B
  const int b = blockIdx.x;
  const int tid = threadIdx.x;
  const int wid = tid >> 6, lane = tid & 63, lg = lane >> 4, lr = lane & 15;
  const int qt = wid;

  const short* wfq = wf;
  const short* wfk = wf + 72 * 64 * 8;
  const short* wfv = wf + 2 * 72 * 64 * 8;
  const f32x4 zero = {0.f, 0.f, 0.f, 0.f};
  const float* xb = x + (size_t)b * (TT * EE);

  // ---- QK B-fragments qb[6] built from Q^T; xq and wqp scoped to die ----
  short8 qb[6];
  {
    short8 xq[6];
#pragma unroll
    for (int es = 0; es < 6; ++es) {
      const float* p = xb + (16 * wid + lr) * EE + 32 * es + 8 * lg;
      float4 u = *(const float4*)p, v = *(const float4*)(p + 4);
      short8 h;
      h[0] = (short)f2bf(u.x); h[1] = (short)f2bf(u.y);
      h[2] = (short)f2bf(u.z); h[3] = (short)f2bf(u.w);
      h[4] = (short)f2bf(v.x); h[5] = (short)f2bf(v.y);
      h[6] = (short)f2bf(v.z); h[7] = (short)f2bf(v.w);
      xq[es] = h;
    }

    {
      unsigned wqp[12][2];
#pragma unroll
      for (int ht = 0; ht < 12; ++ht) {
        f32x4 a = zero;
#pragma unroll
        for (int es = 0; es < 6; ++es) {
          short8 wg = *(const short8*)(wfq + ((size_t)(ht * 6 + es) * 64 + lane) * 8);
          a = __builtin_amdgcn_mfma_f32_16x16x32_bf16(wg, xq[es], a, 0, 0, 0);
        }
        wqp[ht][0] = pack2bf(a[0], a[1]);
        wqp[ht][1] = pack2bf(a[2], a[3]);
      }
      // qb[ha]: lane j -> Q[16qt+lr][32ha+8lg+j]
#pragma unroll
      for (int ha = 0; ha < 6; ++ha) {
        union { unsigned d[4]; short8 v; } au;
#pragma unroll
        for (int i = 0; i < 4; ++i) {
          int sl = ((2 * (lg & 1) + (i >> 1)) << 4) | lr;
          unsigned v0 = (unsigned)__shfl((int)wqp[2 * ha][i & 1], sl);
          unsigned v1 = (unsigned)__shfl((int)wqp[2 * ha + 1][i & 1], sl);
          au.d[i] = (lg >> 1) ? v1 : v0;
        }
        qb[ha] = au.v;
      }
    }

    // ---- K staging: tiles (mt=wid, nt=0..11); xq dies after this ----
#pragma unroll
    for (int nt = 0; nt < 12; ++nt) {
      f32x4 a0 = zero;
#pragma unroll
      for (int es = 0; es < 6; ++es) {
        short8 wg = *(const short8*)(wfk + ((size_t)(nt * 6 + es) * 64 + lane) * 8);
        a0 = __builtin_amdgcn_mfma_f32_16x16x32_bf16(xq[es], wg, a0, 0, 0, 0);
      }
      // K[16*wid+4lg+r][16nt+lr] -> A-frag(kt=wid, ha=nt>>1):
      //   dest lane (lg2=2(nt&1)+(lr>>3), lr2=4lg+r), byte j=lr&7
      int lg2 = 2 * (nt & 1) + (lr >> 3), j = lr & 7;
#pragma unroll
      for (int r = 0; r < 4; ++r)
        *(unsigned short*)(smem +
          (((wid * 6 + (nt >> 1)) * 64 + lg2 * 16 + 4 * lg + r) << 4) + j * 2) = f2bf(a0[r]);
    }
  }
  __syncthreads();  // B1: K fragments visible

  // ---- QK^T unconditional, softmax, pack PV A-frags pa[4] ----
  short8 pa[4];
  {
    f32x4 sa[8];
#pragma unroll
    for (int kt = 0; kt < 8; ++kt) sa[kt] = zero;
#pragma unroll
    for (int kt = 0; kt < 8; ++kt) {
#pragma unroll
      for (int ha = 0; ha < 6; ++ha) {
        short8 ka = *(const short8*)(smem + (((kt * 6 + ha) * 64 + lane) << 4));
        sa[kt] = __builtin_amdgcn_mfma_f32_16x16x32_bf16(ka, qb[ha], sa[kt], 0, 0, 0);
      }
    }

    // softmax over row q=16qt+lr; S^T element (kt,r) is score vs k=16kt+4lg+r
    const float CSC = SCALE_F * LOG2E_F;
    const int q = 16 * qt + lr;
    float m = -INFINITY;
#pragma unroll
    for (int kt = 0; kt < 8; ++kt) {
#pragma unroll
      for (int r = 0; r < 4; ++r) {
        int k = 16 * kt + 4 * lg + r;
        float v = (k <= q) ? sa[kt][r] * CSC : -INFINITY;
        sa[kt][r] = v;
        m = fmaxf(m, v);
      }
    }
    m = fmaxf(m, __shfl_xor(m, 16));
    m = fmaxf(m, __shfl_xor(m, 32));
    float sum = 0.f;
#pragma unroll
    for (int kt = 0; kt < 8; ++kt) {
#pragma unroll
      for (int r = 0; r < 4; ++r) {
        float p = exp2f(sa[kt][r] - m);  // masked -> 0
        sa[kt][r] = p;
        sum += p;
      }
    }
    sum += __shfl_xor(sum, 16);
    sum += __shfl_xor(sum, 32);
    const float rinv = 1.0f / sum;

    unsigned pw[8][2];
#pragma unroll
    for (int kt = 0; kt < 8; ++kt) {
      pw[kt][0] = pack2bf(sa[kt][0] * rinv, sa[kt][1] * rinv);
      pw[kt][1] = pack2bf(sa[kt][2] * rinv, sa[kt][3] * rinv);
    }

    // pa[tp]: lane j -> P[q=16qt+lr][t=32tp+8lg+j]
#pragma unroll
    for (int tp = 0; tp < 4; ++tp) {
      union { unsigned d[4]; short8 v; } au;
#pragma unroll
      for (int i = 0; i < 4; ++i) {
        int sl = ((2 * (lg & 1) + (i >> 1)) << 4) | lr;
        unsigned lo = (unsigned)__shfl((int)pw[2 * tp][i & 1], sl);
        unsigned hi = (unsigned)__shfl((int)pw[2 * tp + 1][i & 1], sl);
        au.d[i] = (lg >> 1) ? hi : lo;
      }
      pa[tp] = au.v;
    }
  }

  // ---- reload x for V staging (pinned here so it doesn't widen QK peak) ----
  __builtin_amdgcn_sched_barrier(0);
  short8 xq2[6];
#pragma unroll
  for (int es = 0; es < 6; ++es) {
    const float* p = xb + (16 * wid + lr) * EE + 32 * es + 8 * lg;
    float4 u = *(const float4*)p, v = *(const float4*)(p + 4);
    short8 h;
    h[0] = (short)f2bf(u.x); h[1] = (short)f2bf(u.y);
    h[2] = (short)f2bf(u.z); h[3] = (short)f2bf(u.w);
    h[4] = (short)f2bf(v.x); h[5] = (short)f2bf(v.y);
    h[6] = (short)f2bf(v.z); h[7] = (short)f2bf(v.w);
    xq2[es] = h;
  }
  __syncthreads();  // B2: all K-fragment reads done; LDS reusable for V

  // ---- V staging into PV B-fragments [tp][ht]: tiles (mt=wid, nt=0..11) ----
#pragma unroll
  for (int nt = 0; nt < 12; ++nt) {
    f32x4 a0 = zero;
#pragma unroll
    for (int es = 0; es < 6; ++es) {
      short8 wg = *(const short8*)(wfv + ((size_t)(nt * 6 + es) * 64 + lane) * 8);
      a0 = __builtin_amdgcn_mfma_f32_16x16x32_bf16(xq2[es], wg, a0, 0, 0, 0);
    }
    // V[16*wid+4lg+r][16nt+lr] -> B-frag(tp=wid>>1, ht=nt):
    //   t_local = 16(wid&1)+4lg+r; dest lane (lg2=t_local>>3, lr2=lr), byte j=t_local&7
    int tl = 16 * (wid & 1) + 4 * lg;
#pragma unroll
    for (int r = 0; r < 4; ++r) {
      int t = tl + r;
      int lg2 = t >> 3, j = t & 7;
      *(unsigned short*)(smem +
        ((((wid >> 1) * 12 + nt) * 64 + lg2 * 16 + lr) << 4) + j * 2) = f2bf(a0[r]);
    }
  }
  __syncthreads();  // B3: V fragments visible

  // ---- PV unconditional (pa zeros mask) in two ht-halves ----
  float* ob = out + (size_t)b * (TT * HH);
#pragma unroll
  for (int half = 0; half < 2; ++half) {
    f32x4 o6[6];
#pragma unroll
    for (int n = 0; n < 6; ++n) o6[n] = zero;
#pragma unroll
    for (int tp = 0; tp < 4; ++tp) {
#pragma unroll
      for (int n = 0; n < 6; ++n) {
        int ht = half * 6 + n;
        short8 bv = *(const short8*)(smem + (((tp * 12 + ht) * 64 + lane) << 4));
        o6[n] = __builtin_amdgcn_mfma_f32_16x16x32_bf16(pa[tp], bv, o6[n], 0, 0, 0);
      }
    }
    // store: lane holds O[16qt+4lg+r][16ht+lr]
#pragma unroll
    for (int n = 0; n < 6; ++n)
#pragma unroll
      for (int r = 0; r < 4; ++r)
        ob[(16 * qt + 4 * lg + r) * HH + (half * 6 + n) * 16 + lr] = o6[n][r];
  }
}

extern "C" void kernel_launch(void* const* d_in, const int* in_sizes, int n_in,
                              void* d_out, int out_size, void* d_ws, size_t ws_size,
                              hipStream_t stream) {
  const float* x  = (const float*)d_in[0];
  const float* Wq = (const float*)d_in[1];
  const float* Wk = (const float*)d_in[2];
  const float* Wv = (const float*)d_in[3];
  float* out = (float*)d_out;
  short* wsW = (short*)d_ws;  // 216 frags x 1KB = 221184 B
  int Bn = in_sizes[0] / (TT * EE);

  hipLaunchKernelGGL(pack_w, dim3(54), dim3(256), 0, stream, Wq, Wk, Wv, wsW);

  // Use the 4-waves/EU build only if it compiled without scratch (no spill).
  // hipFuncGetAttributes is a host-side query: deterministic, capture-safe.
  bool use4 = false;
  hipFuncAttributes fa;
  if (hipFuncGetAttributes(&fa, (const void*)&head_fused<4>) == hipSuccess)
    use4 = (fa.localSizeBytes == 0);

  if (use4)
    hipLaunchKernelGGL(head_fused<4>, dim3(Bn), dim3(512), 49152, stream,
                       x, wsW, out);
  else
    hipLaunchKernelGGL(head_fused<2>, dim3(Bn), dim3(512), 49152, stream,
                       x, wsW, out);
}